// Round 3
// baseline (232.181 us; speedup 1.0000x reference)
//
#include <hip/hip_runtime.h>

// Problem constants (from reference setup_inputs)
#define BB 64
#define NN 128
#define DD 128
#define AA 1000
#define NEG_INF (-9.0e15f)
#define ALPHA_SLOPE 0.2f

// ---------------------------------------------------------------------------
// Kernel 1: attention. Grid BB*(NN/2) x 256 threads. Block: batch b, two query
// rows i = ipair*2 + g (g = tid>>7). LDS: full fp32 h[b] tile, row stride 129
// (odd -> bank rotation; 129 % 32 == 1 so lane j hits bank (j+d) % 32, 2-way
// aliasing only = free on CDNA4).
// out0 is FLOAT32 (reference output dtype) — this was the round-2 bug.
// ---------------------------------------------------------------------------
__global__ __launch_bounds__(256) void attn_kernel(
    const float* __restrict__ hidden,  // [B,N,D] fp32
    const int* __restrict__ adj,       // [B,N,N] int32
    const float* __restrict__ amat,    // [D,4]   fp32
    float* __restrict__ out)           // [B,N,D] fp32
{
    __shared__ __align__(16) float hsf[NN * 129];  // 66048 B
    __shared__ float af[DD * 4];
    __shared__ float attn_s[2 * NN];
    __shared__ float wred[8];

    const int t = threadIdx.x;
    const int g = t >> 7;       // group 0/1 -> query row
    const int lane = t & 127;
    const int b = blockIdx.x >> 6;
    const int ipair = blockIdx.x & 63;
    const int i = ipair * 2 + g;

    // ---- Stage h[b] (16384 fp32) into LDS, coalesced float4 global loads ----
    const float* hb = hidden + (size_t)b * NN * DD;
    #pragma unroll
    for (int it = 0; it < 16; ++it) {
        int e0 = (it * 256 + t) * 4;
        int row = e0 >> 7, col = e0 & 127;
        const float4 v = *reinterpret_cast<const float4*>(hb + e0);
        float* dst = &hsf[row * 129 + col];
        dst[0] = v.x; dst[1] = v.y; dst[2] = v.z; dst[3] = v.w;
    }
    af[t]       = amat[t];
    af[t + 256] = amat[t + 256];
    __syncthreads();

    // ---- Score phase: thread `lane` handles key j = lane ----
    const int j = lane;
    const int ad = adj[((size_t)b * NN + i) * NN + j];
    float alpha = NEG_INF;
    if (ad != 0) {
        const int k = ad - 1;
        float s = 0.f;
        const float* hi = &hsf[i * 129];
        const float* hj = &hsf[j * 129];
        #pragma unroll 8
        for (int d = 0; d < DD; ++d) {
            float p = hi[d] * hj[d];
            p = p > 0.f ? p : ALPHA_SLOPE * p;
            s = fmaf(p, af[d * 4 + k], s);
        }
        alpha = s;
    }

    // ---- Softmax over j (2 waves per group) ----
    const int w = t >> 6;  // wave id 0..3
    float m = alpha;
    #pragma unroll
    for (int off = 32; off > 0; off >>= 1)
        m = fmaxf(m, __shfl_xor(m, off, 64));
    if ((t & 63) == 0) wred[w] = m;
    __syncthreads();
    m = fmaxf(wred[g * 2], wred[g * 2 + 1]);

    // all-masked row: alpha-m == 0 -> ex=1 -> uniform weights (matches jax).
    // clamp guards exp against -inf/NaN args (paranoia; harmless when sane).
    float ex = __expf(fmaxf(alpha - m, -80.0f));
    float ssum = ex;
    #pragma unroll
    for (int off = 32; off > 0; off >>= 1)
        ssum += __shfl_xor(ssum, off, 64);
    if ((t & 63) == 0) wred[4 + w] = ssum;
    __syncthreads();
    ssum = wred[4 + g * 2] + wred[4 + g * 2 + 1];

    attn_s[g * NN + j] = ex / ssum;
    __syncthreads();

    // ---- Output phase: thread `lane` handles feature d = lane ----
    const int d = lane;
    float acc = 0.f;
    const float* at = &attn_s[g * NN];
    #pragma unroll 8
    for (int jj = 0; jj < NN; ++jj)
        acc = fmaf(at[jj], hsf[jj * 129 + d], acc);
    out[((size_t)b * NN + i) * DD + d] = acc;   // fp32 store
}

// ---------------------------------------------------------------------------
// Kernel 2: attr_sess[m,d] = sum_a A_attr[m,a]*emb[a,d]; M=8192,K=1000,N=128.
// 512 blocks x 256 threads; 16 rows/block; K in 8 chunks of 125; A-tile staged
// transposed in LDS so each thread's 8 row-operands = two broadcast
// ds_read_b128. emb reads coalesced, L2-resident (512 KB).
// ---------------------------------------------------------------------------
__global__ __launch_bounds__(256) void attr_kernel(
    const float* __restrict__ Aattr,  // [M,1000] fp32
    const float* __restrict__ emb,    // [1000,128] fp32
    float* __restrict__ out)          // [M,128] fp32
{
    __shared__ __align__(16) float Ast[125 * 16];  // [c][r], 8000 B

    const int t = threadIdx.x;
    const int col = t & 127;
    const int half = t >> 7;          // rows half*8 .. half*8+7
    const int row0 = blockIdx.x * 16;

    float acc[8] = {0.f, 0.f, 0.f, 0.f, 0.f, 0.f, 0.f, 0.f};

    for (int ch = 0; ch < 8; ++ch) {
        __syncthreads();  // protect Ast from previous chunk's readers
        for (int idx = t; idx < 16 * 125; idx += 256) {
            int r = idx / 125;
            int c = idx - r * 125;
            Ast[c * 16 + r] = Aattr[(size_t)(row0 + r) * AA + ch * 125 + c];
        }
        __syncthreads();

        const float* ebase = emb + (size_t)(ch * 125) * 128 + col;
        #pragma unroll 5
        for (int c = 0; c < 125; ++c) {
            float ev = ebase[(size_t)c * 128];
            // 8 fp32 row-operands, 16B-aligned, wave-uniform address (broadcast)
            const float4 a0 = *reinterpret_cast<const float4*>(&Ast[c * 16 + half * 8]);
            const float4 a1 = *reinterpret_cast<const float4*>(&Ast[c * 16 + half * 8 + 4]);
            acc[0] = fmaf(a0.x, ev, acc[0]);
            acc[1] = fmaf(a0.y, ev, acc[1]);
            acc[2] = fmaf(a0.z, ev, acc[2]);
            acc[3] = fmaf(a0.w, ev, acc[3]);
            acc[4] = fmaf(a1.x, ev, acc[4]);
            acc[5] = fmaf(a1.y, ev, acc[5]);
            acc[6] = fmaf(a1.z, ev, acc[6]);
            acc[7] = fmaf(a1.w, ev, acc[7]);
        }
    }

    #pragma unroll
    for (int r = 0; r < 8; ++r)
        out[(size_t)(row0 + half * 8 + r) * 128 + col] = acc[r];
}

extern "C" void kernel_launch(void* const* d_in, const int* in_sizes, int n_in,
                              void* d_out, int out_size, void* d_ws, size_t ws_size,
                              hipStream_t stream) {
    const float* hidden = (const float*)d_in[0];  // [64,128,128] fp32
    const int*   adj    = (const int*)d_in[1];    // [64,128,128] int32
    const float* amat   = (const float*)d_in[2];  // [128,4] fp32
    const float* Aattr  = (const float*)d_in[3];  // [64,128,1000] fp32
    const float* emb    = (const float*)d_in[4];  // [1000,128] fp32

    float* out0 = (float*)d_out;                  // output    [64,128,128] fp32
    float* out1 = out0 + (size_t)BB * NN * DD;    // attr_sess [64,128,128] fp32

    attn_kernel<<<BB * (NN / 2), 256, 0, stream>>>(hidden, adj, amat, out0);
    attr_kernel<<<(BB * NN) / 16, 256, 0, stream>>>(Aattr, emb, out1);
}

// Round 4
// 203.459 us; speedup vs baseline: 1.1412x; 1.1412x over previous
//
#include <hip/hip_runtime.h>

// Problem constants (from reference setup_inputs)
#define BB 64
#define NN 128
#define DD 128
#define AA 1000
#define NEG_INF (-9.0e15f)
#define STRIDE 129   // hsf row stride: (129j+d)%32=(j+d)%32 -> 2-way = free

// ---------------------------------------------------------------------------
// Kernel 1: attention. Grid 64*8 blocks x 256 threads. Block: batch b, 16
// query rows i0..i0+15. LDS: full fp32 h[b] tile (stride 129), attention
// weight matrix W[16][128]. 76 KB LDS -> 2 blocks/CU.
// ---------------------------------------------------------------------------
__global__ __launch_bounds__(256, 2) void attn_kernel(
    const float* __restrict__ hidden,  // [B,N,D] fp32
    const int* __restrict__ adj,       // [B,N,N] int32
    const float* __restrict__ amat,    // [D,4]   fp32
    float* __restrict__ out)           // [B,N,D] fp32
{
    __shared__ __align__(16) float hsf[NN * STRIDE];  // 66048 B
    __shared__ float af[DD * 4];                      // 2048 B
    __shared__ __align__(16) float W[16 * NN];        // 8192 B
    __shared__ float wred[8];

    const int t = threadIdx.x;
    const int g = t >> 7;        // row-group 0/1 within a pass
    const int j = t & 127;       // key index (score) / feature d (output)
    const int w = t >> 6;        // wave id 0..3
    const int b = blockIdx.x >> 3;
    const int i0 = (blockIdx.x & 7) * 16;

    // ---- Prefetch this thread's 8 adjacency values (hides latency) ----
    int adjv[8];
    #pragma unroll
    for (int p = 0; p < 8; ++p) {
        int ip = i0 + p * 2 + g;
        adjv[p] = adj[((size_t)b * NN + ip) * NN + j];
    }

    // ---- Stage h[b] (16384 fp32) into LDS, coalesced float4 loads ----
    const float* hb = hidden + (size_t)b * NN * DD;
    #pragma unroll
    for (int it = 0; it < 16; ++it) {
        int e0 = (it * 256 + t) * 4;
        int row = e0 >> 7, col = e0 & 127;
        const float4 v = *reinterpret_cast<const float4*>(hb + e0);
        float* dst = &hsf[row * STRIDE + col];
        dst[0] = v.x; dst[1] = v.y; dst[2] = v.z; dst[3] = v.w;
    }
    af[t]       = amat[t];
    af[t + 256] = amat[t + 256];
    __syncthreads();

    // ---- Score + softmax: 8 passes of 2 rows (one per group) ----
    #pragma unroll 1
    for (int p = 0; p < 8; ++p) {
        const int ip = i0 + p * 2 + g;
        const int ad = adjv[p];
        float alpha = NEG_INF;
        const float* hi = &hsf[ip * STRIDE];
        const float* hj = &hsf[j * STRIDE];
        if (ad != 0) {
            const int k = ad - 1;
            // 4 independent fma chains (ILP) over the 128-d dot
            float s0 = 0.f, s1 = 0.f, s2 = 0.f, s3 = 0.f;
            for (int d = 0; d < DD; d += 4) {
                float a0 = hi[d]     * hj[d];
                float a1 = hi[d + 1] * hj[d + 1];
                float a2 = hi[d + 2] * hj[d + 2];
                float a3 = hi[d + 3] * hj[d + 3];
                // leaky_relu(x) = max(x, 0.2x)
                a0 = fmaxf(a0, 0.2f * a0);
                a1 = fmaxf(a1, 0.2f * a1);
                a2 = fmaxf(a2, 0.2f * a2);
                a3 = fmaxf(a3, 0.2f * a3);
                s0 = fmaf(a0, af[d * 4 + k], s0);
                s1 = fmaf(a1, af[(d + 1) * 4 + k], s1);
                s2 = fmaf(a2, af[(d + 2) * 4 + k], s2);
                s3 = fmaf(a3, af[(d + 3) * 4 + k], s3);
            }
            alpha = (s0 + s1) + (s2 + s3);
        }

        // softmax over 128 j (2 waves per group)
        float m = alpha;
        #pragma unroll
        for (int off = 32; off > 0; off >>= 1)
            m = fmaxf(m, __shfl_xor(m, off, 64));
        if ((t & 63) == 0) wred[w] = m;
        __syncthreads();
        m = fmaxf(wred[g * 2], wred[g * 2 + 1]);

        // all-masked row: alpha-m == 0 -> uniform weights (matches jax)
        float ex = __expf(fmaxf(alpha - m, -80.0f));
        float ssum = ex;
        #pragma unroll
        for (int off = 32; off > 0; off >>= 1)
            ssum += __shfl_xor(ssum, off, 64);
        if ((t & 63) == 0) wred[4 + w] = ssum;
        __syncthreads();
        ssum = wred[4 + g * 2] + wred[4 + g * 2 + 1];

        W[(p * 2 + g) * NN + j] = ex / ssum;
    }
    __syncthreads();

    // ---- Output: thread (g, d=j) computes rows g*8..g*8+7, feature d ----
    const int d = j;
    float acc[8] = {0.f, 0.f, 0.f, 0.f, 0.f, 0.f, 0.f, 0.f};
    for (int jq = 0; jq < 32; ++jq) {
        const int jj = jq * 4;
        const float hj0 = hsf[jj * STRIDE + d];
        const float hj1 = hsf[(jj + 1) * STRIDE + d];
        const float hj2 = hsf[(jj + 2) * STRIDE + d];
        const float hj3 = hsf[(jj + 3) * STRIDE + d];
        #pragma unroll
        for (int r = 0; r < 8; ++r) {
            // uniform-address broadcast float4 (cheap LDS bc)
            const float4 w4 = *reinterpret_cast<const float4*>(&W[(g * 8 + r) * NN + jj]);
            acc[r] = fmaf(w4.x, hj0, acc[r]);
            acc[r] = fmaf(w4.y, hj1, acc[r]);
            acc[r] = fmaf(w4.z, hj2, acc[r]);
            acc[r] = fmaf(w4.w, hj3, acc[r]);
        }
    }
    #pragma unroll
    for (int r = 0; r < 8; ++r)
        out[((size_t)b * NN + i0 + g * 8 + r) * DD + d] = acc[r];
}

// ---------------------------------------------------------------------------
// Kernel 2: attr_sess = A[8192x1000] * E[1000x128], fp32, register-tiled.
// Grid 512 = 256 row-tiles x 2 K-splits; 256 threads; block tile 32x128,
// thread tile 4x4. LDS: A chunk transposed (pad 36 -> broadcast b128 reads,
// 16B aligned), E chunk contiguous (conflict-free b128). 65.6 KB -> 2 blk/CU.
// Epilogue: fp32 atomicAdd (out zeroed by hipMemsetAsync in kernel_launch).
// ---------------------------------------------------------------------------
#define KC 100
__global__ __launch_bounds__(256, 2) void attr_kernel(
    const float* __restrict__ Aattr,  // [8192,1000] fp32
    const float* __restrict__ emb,    // [1000,128]  fp32
    float* __restrict__ out)          // [8192,128]  fp32 (zero-initialized)
{
    __shared__ __align__(16) float At[KC * 36];    // 14400 B, [k][r] pad 36
    __shared__ __align__(16) float Et[KC * 128];   // 51200 B, [k][c]

    const int t = threadIdx.x;
    const int rb = blockIdx.x >> 1;
    const int ks = blockIdx.x & 1;
    const int row0 = rb * 32;
    const int kb0 = ks * 500;
    const int r0 = (t >> 5) * 4;   // 8 row-groups x 4 rows
    const int c0 = (t & 31) * 4;   // 32 col-groups x 4 cols

    float acc[16];
    #pragma unroll
    for (int i = 0; i < 16; ++i) acc[i] = 0.f;

    for (int ch = 0; ch < 5; ++ch) {
        const int kb = kb0 + ch * KC;
        __syncthreads();
        // Stage A chunk transposed: global coalesced along k (runs of 100)
        for (int idx = t; idx < 32 * KC; idx += 256) {
            int r = idx / KC;
            int kk = idx - r * KC;
            At[kk * 36 + r] = Aattr[(size_t)(row0 + r) * AA + kb + kk];
        }
        // Stage E chunk: float4 coalesced, conflict-free b128 stores
        for (int idx = t; idx < KC * 32; idx += 256) {
            int k = idx >> 5, cq = idx & 31;
            const float4 v = *reinterpret_cast<const float4*>(
                &emb[(size_t)(kb + k) * 128 + cq * 4]);
            *reinterpret_cast<float4*>(&Et[k * 128 + cq * 4]) = v;
        }
        __syncthreads();

        #pragma unroll 4
        for (int k = 0; k < KC; ++k) {
            // A frag: 2 distinct addrs/wave -> broadcast b128; 16B aligned
            const float4 av = *reinterpret_cast<const float4*>(&At[k * 36 + r0]);
            // E frag: 32 contiguous float4 across lanes -> conflict-free
            const float4 ev = *reinterpret_cast<const float4*>(&Et[k * 128 + c0]);
            acc[0]  = fmaf(av.x, ev.x, acc[0]);
            acc[1]  = fmaf(av.x, ev.y, acc[1]);
            acc[2]  = fmaf(av.x, ev.z, acc[2]);
            acc[3]  = fmaf(av.x, ev.w, acc[3]);
            acc[4]  = fmaf(av.y, ev.x, acc[4]);
            acc[5]  = fmaf(av.y, ev.y, acc[5]);
            acc[6]  = fmaf(av.y, ev.z, acc[6]);
            acc[7]  = fmaf(av.y, ev.w, acc[7]);
            acc[8]  = fmaf(av.z, ev.x, acc[8]);
            acc[9]  = fmaf(av.z, ev.y, acc[9]);
            acc[10] = fmaf(av.z, ev.z, acc[10]);
            acc[11] = fmaf(av.z, ev.w, acc[11]);
            acc[12] = fmaf(av.w, ev.x, acc[12]);
            acc[13] = fmaf(av.w, ev.y, acc[13]);
            acc[14] = fmaf(av.w, ev.z, acc[14]);
            acc[15] = fmaf(av.w, ev.w, acc[15]);
        }
    }

    // Epilogue: accumulate the two K-halves via device-scope fp32 atomics
    #pragma unroll
    for (int rr = 0; rr < 4; ++rr)
        #pragma unroll
        for (int cc = 0; cc < 4; ++cc)
            atomicAdd(&out[(size_t)(row0 + r0 + rr) * 128 + c0 + cc],
                      acc[rr * 4 + cc]);
}

extern "C" void kernel_launch(void* const* d_in, const int* in_sizes, int n_in,
                              void* d_out, int out_size, void* d_ws, size_t ws_size,
                              hipStream_t stream) {
    const float* hidden = (const float*)d_in[0];  // [64,128,128] fp32
    const int*   adj    = (const int*)d_in[1];    // [64,128,128] int32
    const float* amat   = (const float*)d_in[2];  // [128,4] fp32
    const float* Aattr  = (const float*)d_in[3];  // [64,128,1000] fp32
    const float* emb    = (const float*)d_in[4];  // [1000,128] fp32

    float* out0 = (float*)d_out;                  // output    [64,128,128] fp32
    float* out1 = out0 + (size_t)BB * NN * DD;    // attr_sess [64,128,128] fp32

    // Zero out1 (harness poisons it 0xAA; attr kernel accumulates atomically)
    hipMemsetAsync(out1, 0, (size_t)BB * NN * DD * sizeof(float), stream);

    attn_kernel<<<BB * 8, 256, 0, stream>>>(hidden, adj, amat, out0);
    attr_kernel<<<512, 256, 0, stream>>>(Aattr, emb, out1);
}

// Round 5
// 109.845 us; speedup vs baseline: 2.1137x; 1.8522x over previous
//
#include <hip/hip_runtime.h>

// Problem constants (from reference setup_inputs)
#define BB 64
#define NN 128
#define DD 128
#define AA 1000
#define KPAD 1024
#define NEG_INF (-9.0e15f)

typedef __attribute__((ext_vector_type(8))) short short8;     // 8 bf16 (4 VGPR) MFMA frag
typedef __attribute__((ext_vector_type(4))) float floatx4;    // MFMA C/D frag
typedef __attribute__((ext_vector_type(4))) unsigned int uintx4;
typedef __attribute__((ext_vector_type(2))) unsigned int uintx2;

__device__ __forceinline__ float bflo(unsigned int u) { return __uint_as_float(u << 16); }
__device__ __forceinline__ float bfhi(unsigned int u) { return __uint_as_float(u & 0xffff0000u); }
// truncating fp32->bf16 pack (cheap; bias ~2^-9 rel, fine vs 1.73 threshold)
__device__ __forceinline__ unsigned int packbf(float f0, float f1) {
  return (__float_as_uint(f0) >> 16) | (__float_as_uint(f1) & 0xffff0000u);
}
// round-to-nearest-even fp32->bf16 (used in prep / softmax weights)
__device__ __forceinline__ unsigned short bf_rne(float f) {
  unsigned int u = __float_as_uint(f);
  return (unsigned short)((u + 0x7fffu + ((u >> 16) & 1u)) >> 16);
}
__device__ __forceinline__ unsigned int packbf_rne(float f0, float f1) {
  return (unsigned int)bf_rne(f0) | ((unsigned int)bf_rne(f1) << 16);
}
__device__ __forceinline__ short8 u2s(uintx4 v) {
  union { uintx4 u; short8 s; } x; x.u = v; return x.s;
}

// ---------------------------------------------------------------------------
// Prep kernel (192 blocks x 256): builds bf16 operand copies in d_ws so both
// MFMA kernels read every fragment k-contiguously.
//  blocks 0..63  : batch b -> Hbf[b][i][d] = bf16(h), HTg[b][d][i] = bf16(h^T)
//  blocks 64..191: row c of ET[c][k] = bf16(emb[k][c]), k zero-padded to 1024
// ---------------------------------------------------------------------------
__global__ __launch_bounds__(256) void prep_kernel(
    const float* __restrict__ hidden, const float* __restrict__ emb,
    unsigned short* __restrict__ ET, unsigned short* __restrict__ Hbf,
    unsigned short* __restrict__ HTg)
{
  const int t = threadIdx.x;
  const int bid = blockIdx.x;
  if (bid < BB) {
    __shared__ float hsf[NN * 129];  // stride 129 -> conflict-free column reads
    const float* hb = hidden + (size_t)bid * NN * DD;
    #pragma unroll
    for (int u = 0; u < 16; ++u) {
      int e = u * 1024 + t * 4;
      float4 v = *reinterpret_cast<const float4*>(hb + e);
      int r = e >> 7, c = e & 127;
      float* d = &hsf[r * 129 + c];
      d[0] = v.x; d[1] = v.y; d[2] = v.z; d[3] = v.w;
    }
    __syncthreads();
    unsigned short* hb16 = Hbf + (size_t)bid * NN * DD;
    unsigned short* ht16 = HTg + (size_t)bid * NN * DD;
    #pragma unroll
    for (int u = 0; u < 8; ++u) {  // Hbf: row-major copy
      int e = u * 2048 + t * 8;
      int r = e >> 7, c = e & 127;
      const float* src = &hsf[r * 129 + c];
      uintx4 o;
      o.x = packbf_rne(src[0], src[1]); o.y = packbf_rne(src[2], src[3]);
      o.z = packbf_rne(src[4], src[5]); o.w = packbf_rne(src[6], src[7]);
      *reinterpret_cast<uintx4*>(hb16 + e) = o;
    }
    #pragma unroll
    for (int u = 0; u < 8; ++u) {  // HTg: transpose via LDS columns
      int e = u * 2048 + t * 8;
      int dI = e >> 7, il = e & 127;
      float x[8];
      #pragma unroll
      for (int j = 0; j < 8; ++j) x[j] = hsf[(il + j) * 129 + dI];
      uintx4 o;
      o.x = packbf_rne(x[0], x[1]); o.y = packbf_rne(x[2], x[3]);
      o.z = packbf_rne(x[4], x[5]); o.w = packbf_rne(x[6], x[7]);
      *reinterpret_cast<uintx4*>(ht16 + e) = o;
    }
  } else {
    int c = bid - BB;       // 0..127
    int k0 = t * 4;         // 0..1020
    float x[4];
    #pragma unroll
    for (int j = 0; j < 4; ++j) {
      int k = k0 + j;
      x[j] = (k < AA) ? emb[(size_t)k * DD + c] : 0.f;
    }
    uintx2 o;
    o.x = packbf_rne(x[0], x[1]);
    o.y = packbf_rne(x[2], x[3]);
    *reinterpret_cast<uintx2*>(ET + (size_t)c * KPAD + k0) = o;
  }
}

// ---------------------------------------------------------------------------
// Attention kernel, full MFMA. 512 blocks (b, 16-row i-tile) x 256 threads.
// lrelu(x)=0.6x+0.4|x| => S_k = (h o 0.6a_k)h^T + (|h| o 0.4a_k)|h|^T :
// one K=256 bf16 GEMM computing all 4 edge-type scores; wave w owns j-quarter,
// all 4 k live in the SAME wave's accs -> in-register adj selection.
// LDS chunks (16B) are XOR-swizzled by row so all ds b128 are <=2-way (free).
// ---------------------------------------------------------------------------
struct AttnSmem {
  __align__(16) unsigned short Hs[NN * 128];      // 32768 B bf16 h (swizzled)
  __align__(16) unsigned short As[4 * 16 * 256];  // 16384 B scaled A rows
  __align__(16) float Sa[16 * 129];               // 8256 B selected scores
  union {
    __align__(16) float saf[4 * 256];             // 4096 B scale table
    __align__(16) unsigned short W[16 * 128];     // 4096 B softmax weights
  } u;
};  // 61504 B total -> 2 blocks/CU

__global__ __launch_bounds__(256, 2) void attn_kernel(
    const int* __restrict__ adj, const float* __restrict__ amat,
    const unsigned short* __restrict__ Hbf,
    const unsigned short* __restrict__ HTg,
    float* __restrict__ out0)
{
  __shared__ AttnSmem s;
  const int t = threadIdx.x;
  const int L = t & 63, w = t >> 6;     // wave w = j-quarter / d-quarter
  const int lr = L & 15, lq = L >> 4;   // MFMA lane coords
  const int b = blockIdx.x >> 3;
  const int i0 = (blockIdx.x & 7) * 16;

  // ---- stage Hs (swizzled: phys chunk = c ^ (row&15)) ----
  const unsigned short* hb = Hbf + (size_t)b * NN * DD;
  #pragma unroll
  for (int u = 0; u < 8; ++u) {
    int id = u * 256 + t;
    int r = id >> 4, c = id & 15;
    uintx4 v = *reinterpret_cast<const uintx4*>(hb + r * 128 + c * 8);
    *reinterpret_cast<uintx4*>(&s.Hs[r * 128 + ((c ^ (r & 15)) << 3)]) = v;
  }
  // ---- scale table: saf[k][d]=0.6*a[d][k], saf[k][128+d]=0.4*a[d][k] ----
  {
    float v1 = amat[t], v2 = amat[t + 256];
    int dI = t >> 2, k = t & 3;
    s.u.saf[k * 256 + dI] = 0.6f * v1;
    s.u.saf[k * 256 + 128 + dI] = 0.4f * v1;
    s.u.saf[k * 256 + 64 + dI] = 0.6f * v2;
    s.u.saf[k * 256 + 192 + dI] = 0.4f * v2;
  }
  __syncthreads();

  // ---- build As[k][i][d'] (d'<128: h*0.6a_k ; d'>=128: |h|*0.4a_k) ----
  #pragma unroll
  for (int u = 0; u < 8; ++u) {
    int id = u * 256 + t;                      // 2048 16B-chunks
    int k = id >> 9, ii = (id >> 5) & 15, c = id & 31;
    int srow = i0 + ii;
    int dchunk = c & 15;
    uintx4 hv = *reinterpret_cast<const uintx4*>(
        &s.Hs[srow * 128 + ((dchunk ^ (srow & 15)) << 3)]);
    if (c & 16) {
      hv.x &= 0x7fff7fffu; hv.y &= 0x7fff7fffu;
      hv.z &= 0x7fff7fffu; hv.w &= 0x7fff7fffu;
    }
    const float* sf = &s.u.saf[k * 256 + c * 8];
    uintx4 o;
    o.x = packbf(bflo(hv.x) * sf[0], bfhi(hv.x) * sf[1]);
    o.y = packbf(bflo(hv.y) * sf[2], bfhi(hv.y) * sf[3]);
    o.z = packbf(bflo(hv.z) * sf[4], bfhi(hv.z) * sf[5]);
    o.w = packbf(bflo(hv.w) * sf[6], bfhi(hv.w) * sf[7]);
    *reinterpret_cast<uintx4*>(&s.As[k * 4096 + ii * 256 + ((c ^ ii) << 3)]) = o;
  }
  __syncthreads();

  // ---- QK: D[i][j] += A_k[i,d'] * B[d'][j], K'=256, 8 MFMA/step ----
  floatx4 acc[4][2];
  #pragma unroll
  for (int k = 0; k < 4; ++k)
    #pragma unroll
    for (int nt = 0; nt < 2; ++nt) acc[k][nt] = floatx4{0.f, 0.f, 0.f, 0.f};

  #pragma unroll
  for (int kt = 0; kt < 8; ++kt) {
    int ca = lq + 4 * kt;            // As chunk 0..31
    short8 afr[4];
    #pragma unroll
    for (int k = 0; k < 4; ++k)
      afr[k] = *reinterpret_cast<const short8*>(
          &s.As[k * 4096 + lr * 256 + ((ca ^ lr) << 3)]);
    int cb = lq + 4 * (kt & 3);      // Hs d-chunk (phase2 re-reads with abs)
    short8 bfr[2];
    #pragma unroll
    for (int nt = 0; nt < 2; ++nt) {
      int jrow = w * 32 + nt * 16 + lr;
      uintx4 hv = *reinterpret_cast<const uintx4*>(
          &s.Hs[jrow * 128 + ((cb ^ (jrow & 15)) << 3)]);
      if (kt >= 4) {
        hv.x &= 0x7fff7fffu; hv.y &= 0x7fff7fffu;
        hv.z &= 0x7fff7fffu; hv.w &= 0x7fff7fffu;
      }
      bfr[nt] = u2s(hv);
    }
    #pragma unroll
    for (int k = 0; k < 4; ++k)
      #pragma unroll
      for (int nt = 0; nt < 2; ++nt)
        acc[k][nt] = __builtin_amdgcn_mfma_f32_16x16x32_bf16(
            afr[k], bfr[nt], acc[k][nt], 0, 0, 0);
  }

  // ---- prefetch PV B-frags from HTg (global, L2-hot; hides latency) ----
  short8 pvb[2][4];
  const unsigned short* ht = HTg + (size_t)b * NN * DD;
  #pragma unroll
  for (int nt = 0; nt < 2; ++nt)
    #pragma unroll
    for (int kt = 0; kt < 4; ++kt) {
      int dI = w * 32 + nt * 16 + lr;
      pvb[nt][kt] = *reinterpret_cast<const short8*>(ht + dI * 128 + kt * 32 + lq * 8);
    }

  // ---- in-register adj selection; C/D: col=lane&15, row=(lane>>4)*4+reg ----
  const int* adjb = adj + ((size_t)b * NN + i0) * NN;
  #pragma unroll
  for (int nt = 0; nt < 2; ++nt)
    #pragma unroll
    for (int r = 0; r < 4; ++r) {
      int ii = lq * 4 + r;
      int j = w * 32 + nt * 16 + lr;
      int ad = adjb[ii * NN + j];
      float al = NEG_INF;
      al = (ad == 1) ? acc[0][nt][r] : al;
      al = (ad == 2) ? acc[1][nt][r] : al;
      al = (ad == 3) ? acc[2][nt][r] : al;
      al = (ad == 4) ? acc[3][nt][r] : al;
      s.Sa[ii * 129 + j] = al;
    }
  __syncthreads();

  // ---- softmax: one full row per wave (lane holds j=L and j=L+64) ----
  #pragma unroll
  for (int p = 0; p < 4; ++p) {
    int ii = w * 4 + p;
    float a1 = s.Sa[ii * 129 + L];
    float a2 = s.Sa[ii * 129 + 64 + L];
    float m = fmaxf(a1, a2);
    #pragma unroll
    for (int off = 32; off > 0; off >>= 1) m = fmaxf(m, __shfl_xor(m, off, 64));
    // all-masked row: a-m==0 -> uniform (matches jax); clamp guards exp
    float e1 = __expf(fmaxf(a1 - m, -80.f));
    float e2 = __expf(fmaxf(a2 - m, -80.f));
    float ss = e1 + e2;
    #pragma unroll
    for (int off = 32; off > 0; off >>= 1) ss += __shfl_xor(ss, off, 64);
    float inv = 1.f / ss;
    int j2 = L + 64;
    s.u.W[ii * 128 + (((L >> 3) ^ ii) << 3) + (L & 7)] = bf_rne(e1 * inv);
    s.u.W[ii * 128 + (((j2 >> 3) ^ ii) << 3) + (j2 & 7)] = bf_rne(e2 * inv);
  }
  __syncthreads();

  // ---- PV: out[i][d] = sum_j W[i,j] * h[j,d]  (B from HTg prefetch) ----
  floatx4 oacc[2];
  oacc[0] = floatx4{0.f, 0.f, 0.f, 0.f};
  oacc[1] = floatx4{0.f, 0.f, 0.f, 0.f};
  #pragma unroll
  for (int kt = 0; kt < 4; ++kt) {
    int c = lq + 4 * kt;
    short8 wf = *reinterpret_cast<const short8*>(
        &s.u.W[lr * 128 + ((c ^ lr) << 3)]);
    #pragma unroll
    for (int nt = 0; nt < 2; ++nt)
      oacc[nt] = __builtin_amdgcn_mfma_f32_16x16x32_bf16(
          wf, pvb[nt][kt], oacc[nt], 0, 0, 0);
  }
  float* ob = out0 + ((size_t)b * NN + i0) * DD;
  #pragma unroll
  for (int nt = 0; nt < 2; ++nt)
    #pragma unroll
    for (int r = 0; r < 4; ++r)
      ob[(lq * 4 + r) * DD + w * 32 + nt * 16 + lr] = oacc[nt][r];
}

// ---------------------------------------------------------------------------
// attr GEMM, MFMA: out1[8192x128] = A[8192x1000] * emb[1000x128] (K pad 1024).
// 256 blocks x 256 thr; block 32x128; wave = 32-col quarter; BK=64 double-
// buffered LDS, ONE barrier/iter; A cvt fp32->bf16 in flight; B from ET
// (pre-transposed bf16) so both frags are k-contig swizzled b128 reads.
// ---------------------------------------------------------------------------
#define BK 64
__global__ __launch_bounds__(256) void attr_kernel(
    const float* __restrict__ Aattr, const unsigned short* __restrict__ ET,
    float* __restrict__ out1)
{
  __shared__ __align__(16) unsigned short ETs[2][DD * BK];  // 2x16384 B
  __shared__ __align__(16) unsigned short As2[2][32 * BK];  // 2x4096 B

  const int t = threadIdx.x;
  const int L = t & 63, w = t >> 6;
  const int lr = L & 15, lq = L >> 4;
  const int r0 = blockIdx.x * 32;

  float4 pa0, pa1;
  uintx4 pe[4];
  const int ar = t >> 3, ak = (t & 7) * 8;     // A fetch coords
  const int ec = t >> 1, ej0 = (t & 1) * 4;    // ET fetch coords

  auto fetch = [&](int it) {
    int kb = it * BK;
    int k4 = kb + ak;
    float4 z = {0.f, 0.f, 0.f, 0.f};
    pa0 = (k4 < AA) ? *reinterpret_cast<const float4*>(Aattr + (size_t)(r0 + ar) * AA + k4) : z;
    pa1 = (k4 + 4 < AA) ? *reinterpret_cast<const float4*>(Aattr + (size_t)(r0 + ar) * AA + k4 + 4) : z;
    #pragma unroll
    for (int q = 0; q < 4; ++q)
      pe[q] = *reinterpret_cast<const uintx4*>(ET + (size_t)ec * KPAD + kb + (ej0 + q) * 8);
  };
  auto stage = [&](int buf) {
    uintx4 o;
    o.x = packbf(pa0.x, pa0.y); o.y = packbf(pa0.z, pa0.w);
    o.z = packbf(pa1.x, pa1.y); o.w = packbf(pa1.z, pa1.w);
    int ac = t & 7;
    *reinterpret_cast<uintx4*>(&As2[buf][ar * BK + ((ac ^ (ar & 7)) << 3)]) = o;
    #pragma unroll
    for (int q = 0; q < 4; ++q)
      *reinterpret_cast<uintx4*>(&ETs[buf][ec * BK + (((ej0 + q) ^ (ec & 7)) << 3)]) = pe[q];
  };

  floatx4 acc[2][2];
  #pragma unroll
  for (int mt = 0; mt < 2; ++mt)
    #pragma unroll
    for (int nt = 0; nt < 2; ++nt) acc[mt][nt] = floatx4{0.f, 0.f, 0.f, 0.f};

  fetch(0);
  for (int it = 0; it < 16; ++it) {
    stage(it & 1);
    __syncthreads();
    if (it < 15) fetch(it + 1);  // overlaps compute below
    #pragma unroll
    for (int ks = 0; ks < 2; ++ks) {
      int c = lq + 4 * ks;
      short8 af[2], bf[2];
      #pragma unroll
      for (int mt = 0; mt < 2; ++mt) {
        int row = mt * 16 + lr;
        af[mt] = *reinterpret_cast<const short8*>(
            &As2[it & 1][row * BK + ((c ^ (row & 7)) << 3)]);
      }
      #pragma unroll
      for (int nt = 0; nt < 2; ++nt) {
        int n = w * 32 + nt * 16 + lr;
        bf[nt] = *reinterpret_cast<const short8*>(
            &ETs[it & 1][n * BK + ((c ^ (n & 7)) << 3)]);
      }
      #pragma unroll
      for (int mt = 0; mt < 2; ++mt)
        #pragma unroll
        for (int nt = 0; nt < 2; ++nt)
          acc[mt][nt] = __builtin_amdgcn_mfma_f32_16x16x32_bf16(
              af[mt], bf[nt], acc[mt][nt], 0, 0, 0);
    }
    // no 2nd barrier: next iter stages the OTHER buffer (2-stage pipeline)
  }

  float* ob = out1 + (size_t)r0 * DD;
  #pragma unroll
  for (int mt = 0; mt < 2; ++mt)
    #pragma unroll
    for (int nt = 0; nt < 2; ++nt)
      #pragma unroll
      for (int r = 0; r < 4; ++r)
        ob[(mt * 16 + lq * 4 + r) * DD + w * 32 + nt * 16 + lr] = acc[mt][nt][r];
}

extern "C" void kernel_launch(void* const* d_in, const int* in_sizes, int n_in,
                              void* d_out, int out_size, void* d_ws, size_t ws_size,
                              hipStream_t stream) {
  const float* hidden = (const float*)d_in[0];  // [64,128,128] fp32
  const int*   adj    = (const int*)d_in[1];    // [64,128,128] int32
  const float* amat   = (const float*)d_in[2];  // [128,4] fp32
  const float* Aattr  = (const float*)d_in[3];  // [64,128,1000] fp32
  const float* emb    = (const float*)d_in[4];  // [1000,128] fp32

  float* out0 = (float*)d_out;                  // output    [64,128,128] fp32
  float* out1 = out0 + (size_t)BB * NN * DD;    // attr_sess [64,128,128] fp32

  // d_ws layout (re-built every call; harness poisons ws): bf16 operands
  unsigned short* ET  = (unsigned short*)d_ws;        // [128][1024]
  unsigned short* Hbf = ET + (size_t)DD * KPAD;       // [64][128][128]
  unsigned short* HTg = Hbf + (size_t)BB * NN * DD;   // [64][128][128]

  prep_kernel<<<BB + DD, 256, 0, stream>>>(hidden, emb, ET, Hbf, HTg);
  attn_kernel<<<BB * 8, 256, 0, stream>>>(adj, amat, Hbf, HTg, out0);
  attr_kernel<<<(BB * NN) / 32, 256, 0, stream>>>(Aattr, ET, out1);
}

// Round 6
// 107.080 us; speedup vs baseline: 2.1683x; 1.0258x over previous
//
#include <hip/hip_runtime.h>

// Problem constants (from reference setup_inputs)
#define BB 64
#define NN 128
#define DD 128
#define AA 1000
#define KPAD 1024
#define NEG_INF (-9.0e15f)

typedef __attribute__((ext_vector_type(8))) short short8;   // 8 bf16 MFMA frag
typedef __attribute__((ext_vector_type(4))) float floatx4;  // MFMA C/D frag
typedef __attribute__((ext_vector_type(4))) unsigned int uintx4;
typedef __attribute__((ext_vector_type(2))) unsigned int uintx2;

__device__ __forceinline__ float bflo(unsigned int u) { return __uint_as_float(u << 16); }
__device__ __forceinline__ float bfhi(unsigned int u) { return __uint_as_float(u & 0xffff0000u); }
// truncating fp32->bf16 pack (cheap; ~2^-9 rel bias, fine vs 1.73 threshold)
__device__ __forceinline__ unsigned int packbf(float f0, float f1) {
  return (__float_as_uint(f0) >> 16) | (__float_as_uint(f1) & 0xffff0000u);
}
// round-to-nearest-even fp32->bf16
__device__ __forceinline__ unsigned short bf_rne(float f) {
  unsigned int u = __float_as_uint(f);
  return (unsigned short)((u + 0x7fffu + ((u >> 16) & 1u)) >> 16);
}
__device__ __forceinline__ unsigned int packbf_rne(float f0, float f1) {
  return (unsigned int)bf_rne(f0) | ((unsigned int)bf_rne(f1) << 16);
}
__device__ __forceinline__ short8 u2s(uintx4 v) {
  union { uintx4 u; short8 s; } x; x.u = v; return x.s;
}

// ---------------------------------------------------------------------------
// Prep (192 blocks x 256): blocks 0..63 -> HTg[b][d][i] = bf16(h[b]^T);
// blocks 64..191 -> ET[c][k] = bf16(emb[k][c]), k zero-padded to 1024.
// (Hbf dropped: attn converts fp32 h in-kernel now.)
// ---------------------------------------------------------------------------
__global__ __launch_bounds__(256) void prep_kernel(
    const float* __restrict__ hidden, const float* __restrict__ emb,
    unsigned short* __restrict__ ET, unsigned short* __restrict__ HTg)
{
  const int t = threadIdx.x;
  const int bid = blockIdx.x;
  if (bid < BB) {
    __shared__ float hsf[NN * 129];
    const float* hb = hidden + (size_t)bid * NN * DD;
    #pragma unroll
    for (int u = 0; u < 16; ++u) {
      int e = u * 1024 + t * 4;
      float4 v = *reinterpret_cast<const float4*>(hb + e);
      int r = e >> 7, c = e & 127;
      float* d = &hsf[r * 129 + c];
      d[0] = v.x; d[1] = v.y; d[2] = v.z; d[3] = v.w;
    }
    __syncthreads();
    unsigned short* ht16 = HTg + (size_t)bid * NN * DD;
    #pragma unroll
    for (int u = 0; u < 8; ++u) {  // transpose via LDS columns
      int e = u * 2048 + t * 8;
      int dI = e >> 7, il = e & 127;
      float x[8];
      #pragma unroll
      for (int j = 0; j < 8; ++j) x[j] = hsf[(il + j) * 129 + dI];
      uintx4 o;
      o.x = packbf_rne(x[0], x[1]); o.y = packbf_rne(x[2], x[3]);
      o.z = packbf_rne(x[4], x[5]); o.w = packbf_rne(x[6], x[7]);
      *reinterpret_cast<uintx4*>(ht16 + e) = o;
    }
  } else {
    int c = bid - BB;       // 0..127
    int k0 = t * 4;
    float x[4];
    #pragma unroll
    for (int j = 0; j < 4; ++j) {
      int k = k0 + j;
      x[j] = (k < AA) ? emb[(size_t)k * DD + c] : 0.f;
    }
    uintx2 o;
    o.x = packbf_rne(x[0], x[1]);
    o.y = packbf_rne(x[2], x[3]);
    *reinterpret_cast<uintx2*>(ET + (size_t)c * KPAD + k0) = o;
  }
}

// ---------------------------------------------------------------------------
// Fused kernel: blocks 0..511 = attention (b, 16-row i-tile); 512..767 = attr
// GEMM (32-row tile). Shared-memory union keeps LDS at ~53 KB -> 3 blocks/CU.
// ---------------------------------------------------------------------------
struct AttnSmem {
  __align__(16) unsigned short Hs[NN * 128];        // 32768 B bf16 h (swizzled)
  union {
    __align__(16) unsigned short As[4 * 16 * 256];  // 16384 B (QK phase only)
    struct {
      __align__(16) float Sa[16 * 129];             // 8256 B (post-QK)
      __align__(16) unsigned short W[16 * 128];     // 4096 B (softmax out)
    } sw;
  } u2;
  __align__(16) float saf[4 * 256];                 // 4096 B scale table
};  // 53248 B

#define BK 64
struct AttrSmem {
  __align__(16) unsigned short ETs[2][DD * BK];     // 32768 B
  __align__(16) unsigned short As2[2][32 * BK];     // 8192 B
};  // 40960 B

union FusedSmem { AttnSmem a; AttrSmem g; };        // 53248 B -> 3 blocks/CU

__device__ __forceinline__ void attn_body(
    AttnSmem& s, const float* __restrict__ hidden,
    const int* __restrict__ adj, const float* __restrict__ amat,
    const unsigned short* __restrict__ HTg, float* __restrict__ out0)
{
  const int t = threadIdx.x;
  const int L = t & 63, w = t >> 6;     // wave w = j-quarter / d-quarter
  const int lr = L & 15, lq = L >> 4;   // MFMA lane coords
  const int b = blockIdx.x >> 3;
  const int i0 = (blockIdx.x & 7) * 16;

  // ---- prefetch adj (in flight under staging) ----
  const int* adjb = adj + ((size_t)b * NN + i0) * NN;
  int adjv[8];
  #pragma unroll
  for (int nt = 0; nt < 2; ++nt)
    #pragma unroll
    for (int r = 0; r < 4; ++r)
      adjv[nt * 4 + r] = adjb[(lq * 4 + r) * NN + w * 32 + nt * 16 + lr];

  // ---- stage Hs from fp32 hidden (convert in flight; swizzle c^(row&15)) ----
  const float* hb = hidden + (size_t)b * NN * DD;
  #pragma unroll
  for (int u = 0; u < 8; ++u) {
    int id = u * 256 + t;
    int r = id >> 4, c = id & 15;
    const float* src = hb + r * 128 + c * 8;
    float4 v0 = *reinterpret_cast<const float4*>(src);
    float4 v1 = *reinterpret_cast<const float4*>(src + 4);
    uintx4 o;
    o.x = packbf_rne(v0.x, v0.y); o.y = packbf_rne(v0.z, v0.w);
    o.z = packbf_rne(v1.x, v1.y); o.w = packbf_rne(v1.z, v1.w);
    *reinterpret_cast<uintx4*>(&s.Hs[r * 128 + ((c ^ (r & 15)) << 3)]) = o;
  }
  // ---- scale table: saf[k][d]=0.6*a[d][k], saf[k][128+d]=0.4*a[d][k] ----
  {
    float v1 = amat[t], v2 = amat[t + 256];
    int dI = t >> 2, k = t & 3;
    s.saf[k * 256 + dI] = 0.6f * v1;
    s.saf[k * 256 + 128 + dI] = 0.4f * v1;
    s.saf[k * 256 + 64 + dI] = 0.6f * v2;
    s.saf[k * 256 + 192 + dI] = 0.4f * v2;
  }
  __syncthreads();

  // ---- build As[k][i][d'] (d'<128: h*0.6a_k ; d'>=128: |h|*0.4a_k) ----
  #pragma unroll
  for (int u = 0; u < 8; ++u) {
    int id = u * 256 + t;
    int k = id >> 9, ii = (id >> 5) & 15, c = id & 31;
    int srow = i0 + ii;
    int dchunk = c & 15;
    uintx4 hv = *reinterpret_cast<const uintx4*>(
        &s.Hs[srow * 128 + ((dchunk ^ (srow & 15)) << 3)]);
    if (c & 16) {
      hv.x &= 0x7fff7fffu; hv.y &= 0x7fff7fffu;
      hv.z &= 0x7fff7fffu; hv.w &= 0x7fff7fffu;
    }
    const float* sf = &s.saf[k * 256 + c * 8];
    uintx4 o;
    o.x = packbf(bflo(hv.x) * sf[0], bfhi(hv.x) * sf[1]);
    o.y = packbf(bflo(hv.y) * sf[2], bfhi(hv.y) * sf[3]);
    o.z = packbf(bflo(hv.z) * sf[4], bfhi(hv.z) * sf[5]);
    o.w = packbf(bflo(hv.w) * sf[6], bfhi(hv.w) * sf[7]);
    *reinterpret_cast<uintx4*>(&s.u2.As[k * 4096 + ii * 256 + ((c ^ ii) << 3)]) = o;
  }
  __syncthreads();

  // ---- QK: all 4 edge-type scores in one K'=256 GEMM, 8 MFMA/step ----
  floatx4 acc[4][2];
  #pragma unroll
  for (int k = 0; k < 4; ++k)
    #pragma unroll
    for (int nt = 0; nt < 2; ++nt) acc[k][nt] = floatx4{0.f, 0.f, 0.f, 0.f};

  #pragma unroll
  for (int kt = 0; kt < 8; ++kt) {
    int ca = lq + 4 * kt;
    short8 afr[4];
    #pragma unroll
    for (int k = 0; k < 4; ++k)
      afr[k] = *reinterpret_cast<const short8*>(
          &s.u2.As[k * 4096 + lr * 256 + ((ca ^ lr) << 3)]);
    int cb = lq + 4 * (kt & 3);
    short8 bfr[2];
    #pragma unroll
    for (int nt = 0; nt < 2; ++nt) {
      int jrow = w * 32 + nt * 16 + lr;
      uintx4 hv = *reinterpret_cast<const uintx4*>(
          &s.Hs[jrow * 128 + ((cb ^ (jrow & 15)) << 3)]);
      if (kt >= 4) {
        hv.x &= 0x7fff7fffu; hv.y &= 0x7fff7fffu;
        hv.z &= 0x7fff7fffu; hv.w &= 0x7fff7fffu;
      }
      bfr[nt] = u2s(hv);
    }
    #pragma unroll
    for (int k = 0; k < 4; ++k)
      #pragma unroll
      for (int nt = 0; nt < 2; ++nt)
        acc[k][nt] = __builtin_amdgcn_mfma_f32_16x16x32_bf16(
            afr[k], bfr[nt], acc[k][nt], 0, 0, 0);
  }
  __syncthreads();  // all As reads done; Sa/W may now overlay As

  // ---- prefetch PV B-frags from HTg (hides under selection/softmax) ----
  short8 pvb[2][4];
  const unsigned short* ht = HTg + (size_t)b * NN * DD;
  #pragma unroll
  for (int nt = 0; nt < 2; ++nt)
    #pragma unroll
    for (int kt = 0; kt < 4; ++kt) {
      int dI = w * 32 + nt * 16 + lr;
      pvb[nt][kt] = *reinterpret_cast<const short8*>(ht + dI * 128 + kt * 32 + lq * 8);
    }

  // ---- in-register adj selection; C/D: col=lane&15, row=(lane>>4)*4+reg ----
  #pragma unroll
  for (int nt = 0; nt < 2; ++nt)
    #pragma unroll
    for (int r = 0; r < 4; ++r) {
      int ii = lq * 4 + r;
      int j = w * 32 + nt * 16 + lr;
      int ad = adjv[nt * 4 + r];
      float al = NEG_INF;
      al = (ad == 1) ? acc[0][nt][r] : al;
      al = (ad == 2) ? acc[1][nt][r] : al;
      al = (ad == 3) ? acc[2][nt][r] : al;
      al = (ad == 4) ? acc[3][nt][r] : al;
      s.u2.sw.Sa[ii * 129 + j] = al;
    }
  __syncthreads();

  // ---- softmax: one full row per wave (lane holds j=L and j=L+64) ----
  #pragma unroll
  for (int p = 0; p < 4; ++p) {
    int ii = w * 4 + p;
    float a1 = s.u2.sw.Sa[ii * 129 + L];
    float a2 = s.u2.sw.Sa[ii * 129 + 64 + L];
    float m = fmaxf(a1, a2);
    #pragma unroll
    for (int off = 32; off > 0; off >>= 1) m = fmaxf(m, __shfl_xor(m, off, 64));
    // all-masked row: a-m==0 -> uniform (matches jax); clamp guards exp
    float e1 = __expf(fmaxf(a1 - m, -80.f));
    float e2 = __expf(fmaxf(a2 - m, -80.f));
    float ss = e1 + e2;
    #pragma unroll
    for (int off = 32; off > 0; off >>= 1) ss += __shfl_xor(ss, off, 64);
    float inv = 1.f / ss;
    int j2 = L + 64;
    s.u2.sw.W[ii * 128 + (((L >> 3) ^ ii) << 3) + (L & 7)] = bf_rne(e1 * inv);
    s.u2.sw.W[ii * 128 + (((j2 >> 3) ^ ii) << 3) + (j2 & 7)] = bf_rne(e2 * inv);
  }
  __syncthreads();

  // ---- PV: out[i][d] = sum_j W[i,j] * h[j,d] (B from HTg prefetch) ----
  floatx4 oacc[2];
  oacc[0] = floatx4{0.f, 0.f, 0.f, 0.f};
  oacc[1] = floatx4{0.f, 0.f, 0.f, 0.f};
  #pragma unroll
  for (int kt = 0; kt < 4; ++kt) {
    int c = lq + 4 * kt;
    short8 wf = *reinterpret_cast<const short8*>(
        &s.u2.sw.W[lr * 128 + ((c ^ lr) << 3)]);
    #pragma unroll
    for (int nt = 0; nt < 2; ++nt)
      oacc[nt] = __builtin_amdgcn_mfma_f32_16x16x32_bf16(
          wf, pvb[nt][kt], oacc[nt], 0, 0, 0);
  }
  float* ob = out0 + ((size_t)b * NN + i0) * DD;
  #pragma unroll
  for (int nt = 0; nt < 2; ++nt)
    #pragma unroll
    for (int r = 0; r < 4; ++r)
      ob[(lq * 4 + r) * DD + w * 32 + nt * 16 + lr] = oacc[nt][r];
}

__device__ __forceinline__ void attr_body(
    AttrSmem& s, const float* __restrict__ Aattr,
    const unsigned short* __restrict__ ET, float* __restrict__ out1)
{
  const int t = threadIdx.x;
  const int L = t & 63, w = t >> 6;
  const int lr = L & 15, lq = L >> 4;
  const int r0 = (blockIdx.x - 512) * 32;

  float4 pa0, pa1;
  uintx4 pe[4];
  const int ar = t >> 3, ak = (t & 7) * 8;
  const int ec = t >> 1, ej0 = (t & 1) * 4;

  auto fetch = [&](int it) {
    int kb = it * BK;
    int k4 = kb + ak;
    float4 z = {0.f, 0.f, 0.f, 0.f};
    pa0 = (k4 < AA) ? *reinterpret_cast<const float4*>(Aattr + (size_t)(r0 + ar) * AA + k4) : z;
    pa1 = (k4 + 4 < AA) ? *reinterpret_cast<const float4*>(Aattr + (size_t)(r0 + ar) * AA + k4 + 4) : z;
    #pragma unroll
    for (int q = 0; q < 4; ++q)
      pe[q] = *reinterpret_cast<const uintx4*>(ET + (size_t)ec * KPAD + kb + (ej0 + q) * 8);
  };
  auto stage = [&](int buf) {
    uintx4 o;
    o.x = packbf(pa0.x, pa0.y); o.y = packbf(pa0.z, pa0.w);
    o.z = packbf(pa1.x, pa1.y); o.w = packbf(pa1.z, pa1.w);
    int ac = t & 7;
    *reinterpret_cast<uintx4*>(&s.As2[buf][ar * BK + ((ac ^ (ar & 7)) << 3)]) = o;
    #pragma unroll
    for (int q = 0; q < 4; ++q)
      *reinterpret_cast<uintx4*>(&s.ETs[buf][ec * BK + (((ej0 + q) ^ (ec & 7)) << 3)]) = pe[q];
  };

  floatx4 acc[2][2];
  #pragma unroll
  for (int mt = 0; mt < 2; ++mt)
    #pragma unroll
    for (int nt = 0; nt < 2; ++nt) acc[mt][nt] = floatx4{0.f, 0.f, 0.f, 0.f};

  fetch(0);
  for (int it = 0; it < 16; ++it) {
    stage(it & 1);
    __syncthreads();
    if (it < 15) fetch(it + 1);  // overlaps compute below
    #pragma unroll
    for (int ks = 0; ks < 2; ++ks) {
      int c = lq + 4 * ks;
      short8 af[2], bf[2];
      #pragma unroll
      for (int mt = 0; mt < 2; ++mt) {
        int row = mt * 16 + lr;
        af[mt] = *reinterpret_cast<const short8*>(
            &s.As2[it & 1][row * BK + ((c ^ (row & 7)) << 3)]);
      }
      #pragma unroll
      for (int nt = 0; nt < 2; ++nt) {
        int n = w * 32 + nt * 16 + lr;
        bf[nt] = *reinterpret_cast<const short8*>(
            &s.ETs[it & 1][n * BK + ((c ^ (n & 7)) << 3)]);
      }
      #pragma unroll
      for (int mt = 0; mt < 2; ++mt)
        #pragma unroll
        for (int nt = 0; nt < 2; ++nt)
          acc[mt][nt] = __builtin_amdgcn_mfma_f32_16x16x32_bf16(
              af[mt], bf[nt], acc[mt][nt], 0, 0, 0);
    }
    // no 2nd barrier: next iter stages the OTHER buffer (2-stage pipeline)
  }

  float* ob = out1 + (size_t)r0 * DD;
  #pragma unroll
  for (int mt = 0; mt < 2; ++mt)
    #pragma unroll
    for (int nt = 0; nt < 2; ++nt)
      #pragma unroll
      for (int r = 0; r < 4; ++r)
        ob[(mt * 16 + lq * 4 + r) * DD + w * 32 + nt * 16 + lr] = acc[mt][nt][r];
}

__global__ __launch_bounds__(256, 3) void fused_kernel(
    const float* __restrict__ hidden, const int* __restrict__ adj,
    const float* __restrict__ amat, const float* __restrict__ Aattr,
    const unsigned short* __restrict__ ET, const unsigned short* __restrict__ HTg,
    float* __restrict__ out0, float* __restrict__ out1)
{
  __shared__ FusedSmem sm;
  if (blockIdx.x < 512) attn_body(sm.a, hidden, adj, amat, HTg, out0);
  else                  attr_body(sm.g, Aattr, ET, out1);
}

extern "C" void kernel_launch(void* const* d_in, const int* in_sizes, int n_in,
                              void* d_out, int out_size, void* d_ws, size_t ws_size,
                              hipStream_t stream) {
  const float* hidden = (const float*)d_in[0];  // [64,128,128] fp32
  const int*   adj    = (const int*)d_in[1];    // [64,128,128] int32
  const float* amat   = (const float*)d_in[2];  // [128,4] fp32
  const float* Aattr  = (const float*)d_in[3];  // [64,128,1000] fp32
  const float* emb    = (const float*)d_in[4];  // [1000,128] fp32

  float* out0 = (float*)d_out;                  // output    [64,128,128] fp32
  float* out1 = out0 + (size_t)BB * NN * DD;    // attr_sess [64,128,128] fp32

  // d_ws layout (rebuilt every call): bf16 operand copies
  unsigned short* ET  = (unsigned short*)d_ws;      // [128][1024]
  unsigned short* HTg = ET + (size_t)DD * KPAD;     // [64][128][128] h^T

  prep_kernel<<<BB + DD, 256, 0, stream>>>(hidden, emb, ET, HTg);
  fused_kernel<<<768, 256, 0, stream>>>(hidden, adj, amat, Aattr, ET, HTg,
                                        out0, out1);
}